// Round 1
// baseline (27.947 us; speedup 1.0000x reference)
//
#include <hip/hip_runtime.h>

// SplatGaussian2D: out[b,c] = sum_n exp(-d2)*opacity*valid * sigmoid(basis(theta) . feat[n,:,c])
// Key identity: sin(theta)=rx*rsqrt(vx^2+vy^2), cos(theta)=ry*rsqrt(...) — no atan2/sincos needed.

constexpr int   BN      = 8192;
constexpr int   NG      = 2048;
constexpr float SMIN    = 1.0f / 30.0f;
constexpr float SSPAN   = (1.0f / 0.75f - 1.0f / 30.0f);   // S_MAX - S_MIN
constexpr float MUSCALE = 1.05f * 256.0f;                  // MU_BORDER * 0.5*W (W=H=512)
constexpr int   BLOCK   = 256;
constexpr int   GCHUNK  = 64;                              // gaussians per block
constexpr int   NSPLIT  = NG / GCHUNK;                     // 32

__global__ __launch_bounds__(BLOCK) void splat2d_kernel(
    const float* __restrict__ xb,   // [B,2]
    const float* __restrict__ xyz,  // [N,2]
    const float* __restrict__ feat, // [N,9,3]
    const float* __restrict__ opac, // [N]
    const float* __restrict__ scal, // [N,2]
    const float* __restrict__ rot,  // [N]
    float* __restrict__ out)        // [B,3]
{
    __shared__ float sp[GCHUNK * 8];    // mx,my,cos,sin,S0,S1,op,pad
    __shared__ float sf[GCHUNK * 28];   // features padded 27->28 (16B-aligned per gaussian)

    const int tid = threadIdx.x;
    const int g0  = blockIdx.y * GCHUNK;

    // --- stage per-gaussian params (one lane per gaussian; wave 0 only) ---
    if (tid < GCHUNK) {
        const int g = g0 + tid;
        float mx = fminf(fmaxf(xyz[2 * g + 0], -1.0f), 1.0f) * MUSCALE;
        float my = fminf(fmaxf(xyz[2 * g + 1], -1.0f), 1.0f) * MUSCALE;
        float s0 = fminf(fmaxf(scal[2 * g + 0], 0.0f), 1.0f) * SSPAN + SMIN;
        float s1 = fminf(fmaxf(scal[2 * g + 1], 0.0f), 1.0f) * SSPAN + SMIN;
        float rr = rot[g];
        float ang = (rr - floorf(rr)) * 6.28318530717958647692f;
        float cs = __cosf(ang);
        float sn = __sinf(ang);
        float op = fminf(fmaxf(opac[g], 0.0f), 1.0f);
        float* p = &sp[tid * 8];
        p[0] = mx; p[1] = my; p[2] = cs; p[3] = sn;
        p[4] = s0; p[5] = s1; p[6] = op; p[7] = 0.0f;
    }
    // --- stage features: GCHUNK*27 contiguous floats, repacked stride 27->28 ---
    for (int i = tid; i < GCHUNK * 27; i += BLOCK) {
        sf[(i / 27) * 28 + (i % 27)] = feat[g0 * 27 + i];
    }
    __syncthreads();

    const int   r  = blockIdx.x * BLOCK + tid;
    const float ax = xb[2 * r + 0] - 256.0f;   // xnorm*0.5*W = x - W/2
    const float ay = xb[2 * r + 1] - 256.0f;

    float o0 = 0.0f, o1 = 0.0f, o2 = 0.0f;

    for (int g = 0; g < GCHUNK; ++g) {
        const float4* p4 = reinterpret_cast<const float4*>(&sp[g * 8]);
        const float4  pa = p4[0];
        const float4  pb = p4[1];
        const float vx = ax - pa.x;
        const float vy = ay - pa.y;
        const float cs = pa.z, sn = pa.w;
        const float rx = cs * vx - sn * vy;
        const float ry = sn * vx + cs * vy;
        const float t0 = pb.x * rx;
        const float t1 = pb.y * ry;
        const float d2 = t0 * t0 + t1 * t1;
        const bool valid = d2 < 25.0f;
        if (__any(valid)) {
            const float w  = valid ? __expf(-d2) * pb.z : 0.0f;
            const float v2 = fmaxf(vx * vx + vy * vy, 1e-24f);
            const float iv = rsqrtf(v2);
            // sin/cos of theta = atan2(rot_x, rot_y) — exact, eps cancels
            const float s1v = rx * iv;
            const float c1v = ry * iv;
            // harmonics by angle-addition (pure FMAs)
            const float s2v = 2.0f * s1v * c1v;
            const float c2v = 1.0f - 2.0f * s1v * s1v;
            const float s3v = s1v * c2v + c1v * s2v;
            const float c3v = c1v * c2v - s1v * s2v;
            const float s4v = 2.0f * s2v * c2v;
            const float c4v = 1.0f - 2.0f * s2v * s2v;

            float fb[28];
            const float4* f4 = reinterpret_cast<const float4*>(&sf[g * 28]);
            #pragma unroll
            for (int q = 0; q < 7; ++q)
                *reinterpret_cast<float4*>(&fb[4 * q]) = f4[q];

            #pragma unroll
            for (int c = 0; c < 3; ++c) {
                float xc = fb[c]
                         + s1v * fb[3 + c]  + c1v * fb[6 + c]
                         + s2v * fb[9 + c]  + c2v * fb[12 + c]
                         + s3v * fb[15 + c] + c3v * fb[18 + c]
                         + s4v * fb[21 + c] + c4v * fb[24 + c];
                float sg = __fdividef(1.0f, 1.0f + __expf(-xc));
                float wv = w * sg;
                if (c == 0) o0 += wv; else if (c == 1) o1 += wv; else o2 += wv;
            }
        }
    }

    atomicAdd(&out[3 * r + 0], o0);
    atomicAdd(&out[3 * r + 1], o1);
    atomicAdd(&out[3 * r + 2], o2);
}

extern "C" void kernel_launch(void* const* d_in, const int* in_sizes, int n_in,
                              void* d_out, int out_size, void* d_ws, size_t ws_size,
                              hipStream_t stream) {
    const float* xb   = (const float*)d_in[0];
    const float* xyz  = (const float*)d_in[1];
    const float* feat = (const float*)d_in[2];
    const float* opac = (const float*)d_in[3];
    const float* scal = (const float*)d_in[4];
    const float* rot  = (const float*)d_in[5];
    float* out = (float*)d_out;

    hipMemsetAsync(out, 0, (size_t)out_size * sizeof(float), stream);
    dim3 grid(BN / BLOCK, NSPLIT);
    splat2d_kernel<<<grid, dim3(BLOCK, 1, 1), 0, stream>>>(xb, xyz, feat, opac, scal, rot, out);
}